// Round 4
// baseline (68.484 us; speedup 1.0000x reference)
//
#include <hip/hip_runtime.h>

#define IN_C 192
#define HW   9600   // 80*120
#define NPIX 64     // pixels per block (4 waves x 16-px strips)

typedef __attribute__((ext_vector_type(8))) short bf16x8;
typedef __attribute__((ext_vector_type(4))) float f32x4;

static __device__ __forceinline__ short f2bf(float f) {
  // round-to-nearest-even fp32 -> bf16 (inputs are finite normals)
  unsigned u = __builtin_bit_cast(unsigned, f);
  u += 0x7FFFu + ((u >> 16) & 1u);
  return (short)(u >> 16);
}

// Pack W (192x192 fp32, row-major [o][k]) into fragment-sequential bf16:
// frag (fo, kk): 64 lanes x 8 bf16 (16B/lane), lane l -> o = fo*16 + (l&15),
// k = kk*32 + (l>>4)*8 + j. Same k(l,j) convention as the x B-frags, so any
// true intra-fragment k-permutation of the HW layout cancels (validated R1).
__global__ void pack_w_kernel(const float* __restrict__ W, short* __restrict__ wp) {
  int idx = blockIdx.x * 256 + threadIdx.x;   // 0 .. 12*6*64-1 = 4607
  if (idx >= 12 * 6 * 64) return;
  int fo  = idx / (6 * 64);
  int rem = idx % (6 * 64);
  int kk  = rem / 64;
  int l   = rem % 64;
  int o   = fo * 16 + (l & 15);
  int kb  = kk * 32 + (l >> 4) * 8;
  bf16x8 v;
#pragma unroll
  for (int j = 0; j < 8; ++j) v[j] = f2bf(W[o * IN_C + kb + j]);
  *reinterpret_cast<bf16x8*>(wp + (size_t)idx * 8) = v;
}

// Per-pixel GEMM D[o][p] = sum_k W[o][k]*x[b][k][p] + bias[o], sub-block scatter.
// No LDS, no barriers. Out-channels split across 2 blocks (6 frags each ->
// acc 24 regs); total unified regs ~100 -> 4 blocks/CU. Depth-2 register
// prefetch of x (3 named rotating buffers). Adjacent blocks (bx&1) share the
// same x tile -> second read is L2/L3-served.
__global__ __launch_bounds__(256, 4) void conv_mfma_kernel(
    const float* __restrict__ x, const short* __restrict__ wp,
    const float* __restrict__ bias, float* __restrict__ out) {
  const int tid  = threadIdx.x;
  const int wid  = tid >> 6;
  const int lane = tid & 63;
  const int c    = lane & 15;
  const int g    = lane >> 4;
  const int b    = blockIdx.y;
  const int bx   = blockIdx.x;
  const int half = bx & 1;            // which 96 out-channels
  const int fo0  = half * 6;
  const int p    = (bx >> 1) * NPIX + wid * 16 + c;   // this lane's pixel

  // lane's x column base: k = kk*32 + g*8 + j  ->  xp[(kk*32 + j)*HW]
  const float* xp = x + (size_t)b * IN_C * HW + (size_t)(g * 8) * HW + p;

  f32x4 acc[6];
#pragma unroll
  for (int m = 0; m < 6; ++m) acc[m] = (f32x4)0.0f;

  float xa[8], xb_[8], xc[8];

#define LOADX(DST, KK)                                                \
  { _Pragma("unroll")                                                 \
    for (int j = 0; j < 8; ++j)                                       \
      DST[j] = xp[(size_t)((KK) * 32 + j) * HW]; }

#define KSTEP(CURB, PFB, KK)                                          \
  {                                                                   \
    if ((KK) + 2 < 6) { LOADX(PFB, (KK) + 2); }                       \
    bf16x8 af[6];                                                     \
    _Pragma("unroll")                                                 \
    for (int m = 0; m < 6; ++m)                                       \
      af[m] = *reinterpret_cast<const bf16x8*>(                       \
          wp + (size_t)((((fo0 + m) * 6 + (KK)) * 64) + lane) * 8);   \
    bf16x8 bfr;                                                       \
    _Pragma("unroll")                                                 \
    for (int j = 0; j < 8; ++j) bfr[j] = f2bf(CURB[j]);               \
    _Pragma("unroll")                                                 \
    for (int m = 0; m < 6; ++m)                                       \
      acc[m] = __builtin_amdgcn_mfma_f32_16x16x32_bf16(               \
          af[m], bfr, acc[m], 0, 0, 0);                               \
  }

  LOADX(xa, 0);
  LOADX(xb_, 1);
  KSTEP(xa,  xc,  0);   // prefetch k2 -> xc
  KSTEP(xb_, xa,  1);   // prefetch k3 -> xa
  KSTEP(xc,  xb_, 2);   // prefetch k4 -> xb_
  KSTEP(xa,  xc,  3);   // prefetch k5 -> xc
  KSTEP(xb_, xa,  4);
  KSTEP(xc,  xb_, 5);
#undef KSTEP
#undef LOADX

  // Epilogue: C/D col = lane&15 (pixel, == c), row = g*4 + r (out-ch).
  const int hi = p / 120;
  const int wi = p - hi * 120;
#pragma unroll
  for (int m = 0; m < 6; ++m) {
    const int ob = (fo0 + m) * 16 + g * 4;
    const f32x4 bv = *reinterpret_cast<const f32x4*>(bias + ob);
    const f32x4 v  = acc[m];
#pragma unroll
    for (int r = 0; r < 4; ++r) {
      const int o  = ob + r;
      const int co = o >> 6;
      const int br = (o >> 3) & 7;
      const int bc = o & 7;
      const int idx = ((b * 3 + co) * 640 + br * 80 + hi) * 960 + bc * 120 + wi;
      out[idx] = v[r] + bv[r];
    }
  }
}

extern "C" void kernel_launch(void* const* d_in, const int* in_sizes, int n_in,
                              void* d_out, int out_size, void* d_ws, size_t ws_size,
                              hipStream_t stream) {
  const float* x    = (const float*)d_in[0];
  const float* W    = (const float*)d_in[1];
  const float* bias = (const float*)d_in[2];
  float* out = (float*)d_out;
  short* wp  = (short*)d_ws;   // 192*192 bf16 packed-fragment W (73728 B)

  pack_w_kernel<<<18, 256, 0, stream>>>(W, wp);
  dim3 grid(300, 16);  // 150 pixel tiles x 2 och-halves, 16 batches
  conv_mfma_kernel<<<grid, 256, 0, stream>>>(x, wp, bias, out);
}

// Round 5
// 58.360 us; speedup vs baseline: 1.1735x; 1.1735x over previous
//
#include <hip/hip_runtime.h>

#define IN_C 192
#define HW   9600   // 80*120
#define NPIX 64     // pixels per block (4 waves x 16-px strips)
#define PITCH 65    // LDS row pitch in floats (65 mod 32 = 1 -> bank-stagger)

typedef __attribute__((ext_vector_type(8))) short bf16x8;
typedef __attribute__((ext_vector_type(4))) float f32x4;

static __device__ __forceinline__ short f2bf(float f) {
  // round-to-nearest-even fp32 -> bf16 (inputs are finite normals)
  unsigned u = __builtin_bit_cast(unsigned, f);
  u += 0x7FFFu + ((u >> 16) & 1u);
  return (short)(u >> 16);
}

// Pack W (192x192 fp32, row-major [o][k]) into fragment-sequential bf16:
// frag (fo, kk): 64 lanes x 8 bf16 (16B/lane), lane l -> o = fo*16 + (l&15),
// k = kk*32 + (l>>4)*8 + j. Same k(l,j) convention as the x B-frags, so any
// true intra-fragment k-permutation of the HW layout cancels (validated R1).
__global__ void pack_w_kernel(const float* __restrict__ W, short* __restrict__ wp) {
  int idx = blockIdx.x * 256 + threadIdx.x;   // 0 .. 12*6*64-1 = 4607
  if (idx >= 12 * 6 * 64) return;
  int fo  = idx / (6 * 64);
  int rem = idx % (6 * 64);
  int kk  = rem / 64;
  int l   = rem % 64;
  int o   = fo * 16 + (l & 15);
  int kb  = kk * 32 + (l >> 4) * 8;
  bf16x8 v;
#pragma unroll
  for (int j = 0; j < 8; ++j) v[j] = f2bf(W[o * IN_C + kb + j]);
  *reinterpret_cast<bf16x8*>(wp + (size_t)idx * 8) = v;
}

// Per-pixel GEMM D[o][p] = sum_k W[o][k]*x[b][k][p] + bias[o], sub-block scatter.
// x read ONCE (R4 lesson: K-replication across blocks costs real HBM fetch).
// 2-phase async-LDS pipeline (T3 minimum): stage(kk+1) via global_load_lds
// (fire-and-forget, no VGPR landing) issued before compute(kk); one
// __syncthreads per step (its implicit vmcnt(0) drain is the per-tile wait,
// covered by ~4 resident blocks/CU). Rows staged linearly at pitch 65 ->
// ds_read_b32 B-frag reads are 2-way bank conflicts (free).
__global__ __launch_bounds__(256, 4) void conv_mfma_kernel(
    const float* __restrict__ x, const short* __restrict__ wp,
    const float* __restrict__ bias, float* __restrict__ out) {
  __shared__ float sx[2][32 * PITCH];   // 2 x 8.32 KB

  const int tid  = threadIdx.x;
  const int wid  = tid >> 6;
  const int lane = tid & 63;
  const int c    = lane & 15;
  const int g    = lane >> 4;
  const int b    = blockIdx.y;
  const int ptile = blockIdx.x * NPIX;

  // row base for this block's pixel window; lane l copies word l of a row
  const float* xb = x + (size_t)b * IN_C * HW + ptile;

  f32x4 acc[12];
#pragma unroll
  for (int m = 0; m < 12; ++m) acc[m] = (f32x4)0.0f;

  // STAGE: wave wid copies k-rows [wid*8, wid*8+8) of the 32-row tile.
  // Per instr: 64 lanes x 4B = one 256B row; LDS dest linear (base + lane*4).
#define STAGE(BUF, KK)                                                \
  { _Pragma("unroll")                                                 \
    for (int r = 0; r < 8; ++r) {                                     \
      const int row = wid * 8 + r;                                    \
      const float* src = xb + (size_t)((KK) * 32 + row) * HW + lane;  \
      float* dst = &sx[(BUF)][row * PITCH];                           \
      __builtin_amdgcn_global_load_lds(                               \
          (const __attribute__((address_space(1))) void*)src,         \
          (__attribute__((address_space(3))) void*)dst, 4, 0, 0);     \
    } }

  STAGE(0, 0);
  __syncthreads();   // buf0 staged (implicit vmcnt(0) drain before barrier)

#pragma unroll
  for (int kk = 0; kk < 6; ++kk) {
    const int cur = kk & 1;
    if (kk < 5) STAGE(cur ^ 1, kk + 1);   // issue next tile, then compute

    // B-frag: lane needs x[k = g*8+j][px = wid*16+c] from LDS.
    // bank = (g*8+j + wid*16 + c) & 31 -> 2 lanes/bank (free).
    bf16x8 bfr;
#pragma unroll
    for (int j = 0; j < 8; ++j)
      bfr[j] = f2bf(sx[cur][(g * 8 + j) * PITCH + wid * 16 + c]);

    // A-frags: packed W from global (L2-resident), 2 batches of 6
#pragma unroll
    for (int h = 0; h < 2; ++h) {
      bf16x8 af[6];
#pragma unroll
      for (int m = 0; m < 6; ++m)
        af[m] = *reinterpret_cast<const bf16x8*>(
            wp + (size_t)((((h * 6 + m) * 6 + kk) * 64) + lane) * 8);
#pragma unroll
      for (int m = 0; m < 6; ++m)
        acc[h * 6 + m] = __builtin_amdgcn_mfma_f32_16x16x32_bf16(
            af[m], bfr, acc[h * 6 + m], 0, 0, 0);
    }

    __syncthreads();   // stage(kk+1) landed + all reads of buf[cur] done
  }
#undef STAGE

  // Epilogue: C/D col = lane&15 (pixel, == c), row = g*4 + r (out-ch).
  const int p  = ptile + wid * 16 + c;
  const int hi = p / 120;
  const int wi = p - hi * 120;
#pragma unroll
  for (int mo = 0; mo < 12; ++mo) {
    const int ob = mo * 16 + g * 4;
    const f32x4 bv = *reinterpret_cast<const f32x4*>(bias + ob);
    const f32x4 v  = acc[mo];
#pragma unroll
    for (int r = 0; r < 4; ++r) {
      const int o  = ob + r;
      const int co = o >> 6;
      const int br = (o >> 3) & 7;
      const int bc = o & 7;
      const int idx = ((b * 3 + co) * 640 + br * 80 + hi) * 960 + bc * 120 + wi;
      out[idx] = v[r] + bv[r];
    }
  }
}

extern "C" void kernel_launch(void* const* d_in, const int* in_sizes, int n_in,
                              void* d_out, int out_size, void* d_ws, size_t ws_size,
                              hipStream_t stream) {
  const float* x    = (const float*)d_in[0];
  const float* W    = (const float*)d_in[1];
  const float* bias = (const float*)d_in[2];
  float* out = (float*)d_out;
  short* wp  = (short*)d_ws;   // 192*192 bf16 packed-fragment W (73728 B)

  pack_w_kernel<<<18, 256, 0, stream>>>(W, wp);
  dim3 grid(150, 16);  // 150 pixel tiles of 64 (9600 exact), 16 batches
  conv_mfma_kernel<<<grid, 256, 0, stream>>>(x, wp, bias, out);
}

// Round 6
// 48.985 us; speedup vs baseline: 1.3980x; 1.1914x over previous
//
#include <hip/hip_runtime.h>

#define IN_C 192
#define HW   9600   // 80*120
#define NPIX 128    // pixels per block (8 waves x 16-px strips)

typedef __attribute__((ext_vector_type(8))) short bf16x8;
typedef __attribute__((ext_vector_type(4))) float f32x4;

static __device__ __forceinline__ short f2bf(float f) {
  // round-to-nearest-even fp32 -> bf16 (inputs are finite normals)
  unsigned u = __builtin_bit_cast(unsigned, f);
  u += 0x7FFFu + ((u >> 16) & 1u);
  return (short)(u >> 16);
}

// Pack W (192x192 fp32, row-major [o][k]) into fragment-sequential bf16:
// frag (fo, kk): 64 lanes x 8 bf16 (16B/lane), lane l -> o = fo*16 + (l&15),
// k = kk*32 + (l>>4)*8 + j. Same k(l,j) convention as the x B-frags, so any
// true intra-fragment k-permutation of the HW layout cancels (validated R1).
__global__ void pack_w_kernel(const float* __restrict__ W, short* __restrict__ wp) {
  int idx = blockIdx.x * 256 + threadIdx.x;   // 0 .. 12*6*64-1 = 4607
  if (idx >= 12 * 6 * 64) return;
  int fo  = idx / (6 * 64);
  int rem = idx % (6 * 64);
  int kk  = rem / 64;
  int l   = rem % 64;
  int o   = fo * 16 + (l & 15);
  int kb  = kk * 32 + (l >> 4) * 8;
  bf16x8 v;
#pragma unroll
  for (int j = 0; j < 8; ++j) v[j] = f2bf(W[o * IN_C + kb + j]);
  *reinterpret_cast<bf16x8*>(wp + (size_t)idx * 8) = v;
}

// Per-pixel GEMM D[o][p] = sum_k W[o][k]*x[b][k][p] + bias[o], sub-block scatter.
// R5 lesson (vmcnt FIFO): A-frag GLOBAL loads after the x-prefetch forced the
// compiler's pre-MFMA vmcnt wait to retire the in-flight HBM prefetch every
// step. Fix: W lives in LDS (lgkmcnt stream) -> the K-loop's ONLY vmcnt ops
// are x prefetches; depth-2 register rotation stays in flight. No barriers in
// the K-loop (W staged once in the prologue). x is read exactly once.
__global__ __launch_bounds__(512, 4) void conv_mfma_kernel(
    const float* __restrict__ x, const short* __restrict__ wp,
    const float* __restrict__ bias, float* __restrict__ out) {
  __shared__ short wl[12 * 6 * 64 * 8];   // 73728 B packed-fragment W

  const int tid  = threadIdx.x;
  const int wid  = tid >> 6;
  const int lane = tid & 63;
  const int c    = lane & 15;
  const int g    = lane >> 4;
  const int b    = blockIdx.y;
  const int p    = blockIdx.x * NPIX + wid * 16 + c;   // this lane's pixel

  // ---- Prologue: stage packed W -> LDS (L2-resident source), one barrier ----
  // chunk = i*512 + tid; dest = chunk*16 bytes (wave-uniform base + lane*16).
#pragma unroll
  for (int i = 0; i < 9; ++i) {
    const int chunk = i * 512 + tid;
    const short* src = wp + (size_t)chunk * 8;
    short* dst = wl + (size_t)chunk * 8;
    __builtin_amdgcn_global_load_lds(
        (const __attribute__((address_space(1))) void*)src,
        (__attribute__((address_space(3))) void*)dst, 16, 0, 0);
  }
  __syncthreads();   // drains the staging loads; K-loop is barrier-free

  // lane's x column base: k = kk*32 + g*8 + j  ->  xp[(kk*32 + j)*HW]
  const float* xp = x + (size_t)b * IN_C * HW + (size_t)(g * 8) * HW + p;

  f32x4 acc[12];
#pragma unroll
  for (int m = 0; m < 12; ++m) acc[m] = (f32x4)0.0f;

  float xa[8], xb_[8], xc[8];

#define LOADX(DST, KK)                                                \
  { _Pragma("unroll")                                                 \
    for (int j = 0; j < 8; ++j)                                       \
      DST[j] = xp[(size_t)((KK) * 32 + j) * HW]; }

  // af from LDS in batches of 3 (12 transient VGPRs) to bound pressure.
#define KSTEP(CURB, PFB, KK)                                          \
  {                                                                   \
    if ((KK) + 2 < 6) { LOADX(PFB, (KK) + 2); }                       \
    bf16x8 bfr;                                                       \
    _Pragma("unroll")                                                 \
    for (int j = 0; j < 8; ++j) bfr[j] = f2bf(CURB[j]);               \
    _Pragma("unroll")                                                 \
    for (int h = 0; h < 4; ++h) {                                     \
      bf16x8 af[3];                                                   \
      _Pragma("unroll")                                               \
      for (int m = 0; m < 3; ++m)                                     \
        af[m] = *reinterpret_cast<const bf16x8*>(                     \
            wl + (size_t)((((h * 3 + m) * 6 + (KK)) * 64) + lane) * 8); \
      _Pragma("unroll")                                               \
      for (int m = 0; m < 3; ++m)                                     \
        acc[h * 3 + m] = __builtin_amdgcn_mfma_f32_16x16x32_bf16(     \
            af[m], bfr, acc[h * 3 + m], 0, 0, 0);                     \
    }                                                                 \
  }

  LOADX(xa, 0);
  LOADX(xb_, 1);
  KSTEP(xa,  xc,  0);   // prefetch k2 -> xc
  KSTEP(xb_, xa,  1);   // prefetch k3 -> xa
  KSTEP(xc,  xb_, 2);   // prefetch k4 -> xb_
  KSTEP(xa,  xc,  3);   // prefetch k5 -> xc
  KSTEP(xb_, xa,  4);
  KSTEP(xc,  xb_, 5);
#undef KSTEP
#undef LOADX

  // Epilogue: C/D col = lane&15 (pixel, == c), row = g*4 + r (out-ch).
  const int hi = p / 120;
  const int wi = p - hi * 120;
#pragma unroll
  for (int mo = 0; mo < 12; ++mo) {
    const int ob = mo * 16 + g * 4;
    const f32x4 bv = *reinterpret_cast<const f32x4*>(bias + ob);
    const f32x4 v  = acc[mo];
#pragma unroll
    for (int r = 0; r < 4; ++r) {
      const int o  = ob + r;
      const int co = o >> 6;
      const int br = (o >> 3) & 7;
      const int bc = o & 7;
      const int idx = ((b * 3 + co) * 640 + br * 80 + hi) * 960 + bc * 120 + wi;
      out[idx] = v[r] + bv[r];
    }
  }
}

extern "C" void kernel_launch(void* const* d_in, const int* in_sizes, int n_in,
                              void* d_out, int out_size, void* d_ws, size_t ws_size,
                              hipStream_t stream) {
  const float* x    = (const float*)d_in[0];
  const float* W    = (const float*)d_in[1];
  const float* bias = (const float*)d_in[2];
  float* out = (float*)d_out;
  short* wp  = (short*)d_ws;   // 192*192 bf16 packed-fragment W (73728 B)

  pack_w_kernel<<<18, 256, 0, stream>>>(W, wp);
  dim3 grid(75, 16);  // 75 pixel tiles of 128 (9600 exact), 16 batches
  conv_mfma_kernel<<<grid, 512, 0, stream>>>(x, wp, bias, out);
}